// Round 3
// baseline (300.858 us; speedup 1.0000x reference)
//
#include <hip/hip_runtime.h>

typedef __attribute__((ext_vector_type(4))) float f32x4;
typedef __attribute__((ext_vector_type(8))) short s16x8;
typedef __attribute__((ext_vector_type(4))) short s16x4;
typedef __bf16 bf16x4 __attribute__((ext_vector_type(4)));

#define B_   96
#define NQ   35
#define LP   180
#define H_   768
#define D_   128
#define NEGF (-1e30f)

#define NROWS 37920
#define QROWS 3360
#define PROWS 17280

__device__ __forceinline__ unsigned short f2bf(float f) {
    return __builtin_bit_cast(unsigned short, (__bf16)f);
}

// split two f32x4 into bf16 hi + lo fragments (native packed cvt on gfx950)
__device__ __forceinline__ void cvt_hilo(f32x4 v0, f32x4 v1, s16x8* hi, s16x8* lo) {
    bf16x4 h0 = __builtin_convertvector(v0, bf16x4);
    bf16x4 h1 = __builtin_convertvector(v1, bf16x4);
    f32x4 r0 = v0 - __builtin_convertvector(h0, f32x4);
    f32x4 r1 = v1 - __builtin_convertvector(h1, f32x4);
    bf16x4 l0 = __builtin_convertvector(r0, bf16x4);
    bf16x4 l1 = __builtin_convertvector(r1, bf16x4);
    s16x4 h0s = __builtin_bit_cast(s16x4, h0), h1s = __builtin_bit_cast(s16x4, h1);
    s16x4 l0s = __builtin_bit_cast(s16x4, l0), l1s = __builtin_bit_cast(s16x4, l1);
    *hi = __builtin_shufflevector(h0s, h1s, 0, 1, 2, 3, 4, 5, 6, 7);
    *lo = __builtin_shufflevector(l0s, l1s, 0, 1, 2, 3, 4, 5, 6, 7);
}

// ---------------- mask dtype detection + canonicalization ----------------
__global__ void mask_detect(const unsigned char* __restrict__ mp, unsigned int* __restrict__ ctrl) {
    int i = blockIdx.x * 256 + threadIdx.x;
    if (i >= B_ * LP) return;
    unsigned char v = mp[i];
    if (v) {
        if ((i & 3) == 1) atomicAdd(&ctrl[0], 1u);  // 1-byte layout (bool/int8)
        if ((i & 3) == 3) atomicAdd(&ctrl[1], 1u);  // float32
        if ((i & 7) == 4) atomicAdd(&ctrl[2], 1u);  // int32
    }
}

__global__ void mask_canon(const void* __restrict__ pm, const void* __restrict__ nm,
                           const unsigned int* __restrict__ ctrl, unsigned char* __restrict__ outm) {
    int i = blockIdx.x * 256 + threadIdx.x;
    if (i >= 2 * B_ * LP) return;
    const void* src = (i < B_ * LP) ? pm : nm;
    int j = (i < B_ * LP) ? i : i - B_ * LP;
    unsigned int c1 = ctrl[0], c3 = ctrl[1], c4 = ctrl[2];
    bool bit;
    if (c1 > 0)       bit = ((const unsigned char*)src)[j] != 0;
    else if (c3 > 0)  bit = ((const float*)src)[j] != 0.0f;
    else if (c4 > 0)  bit = ((const int*)src)[j] != 0;
    else              bit = ((const long long*)src)[j] != 0;
    outm[i] = bit ? 1 : 0;
}

// ---------------- W -> fragment-ordered bf16 (hi only) ----------------
__global__ void wt_build(const float* __restrict__ W, unsigned short* __restrict__ wthi) {
    int tid = blockIdx.x * 256 + threadIdx.x;            // 12288 total
    int nt = tid / (24 * 64);
    int r = tid - nt * 24 * 64;
    int ks = r / 64, lane = r - ks * 64;
    int m = lane & 15, quad = lane >> 4;
    unsigned short* o = wthi + (size_t)tid * 8;
#pragma unroll
    for (int j = 0; j < 8; j++) {
        int k = ks * 32 + quad * 8 + j;
        o[j] = f2bf(W[(size_t)k * D_ + nt * 16 + m]);
    }
}

// ---------------- projection GEMM: 16-row tiles, K-split x2 ----------------
// wave w: rg = w>>1 (16-row group, 2370 total), kh = w&1 (K half).
__global__ __launch_bounds__(256) void proj_k(
    const float* __restrict__ qh, const float* __restrict__ ph, const float* __restrict__ nh,
    const unsigned short* __restrict__ wthi, const float* __restrict__ bias,
    float* __restrict__ x0, float* __restrict__ x1) {
    int wave = threadIdx.x >> 6, lane = threadIdx.x & 63;
    int w = blockIdx.x * 4 + wave;                       // 4740 exactly
    int rg = w >> 1, kh = w & 1;
    const float* src; int row0l; size_t growbase;
    if (rg < 210)       { src = qh; row0l = rg * 16;          growbase = row0l; }
    else if (rg < 1290) { src = ph; row0l = (rg - 210) * 16;  growbase = QROWS + row0l; }
    else                { src = nh; row0l = (rg - 1290) * 16; growbase = QROWS + PROWS + row0l; }
    float* dst = kh ? x1 : x0;
    int m = lane & 15, quad = lane >> 4;
    const float* ap = src + (size_t)(row0l + m) * H_ + kh * 384 + quad * 8;

    f32x4 acc[8];
#pragma unroll
    for (int nt = 0; nt < 8; nt++) acc[nt] = (f32x4){0.f, 0.f, 0.f, 0.f};

#pragma unroll 2
    for (int kl = 0; kl < 12; kl++) {
        const f32x4* pA = (const f32x4*)(ap + kl * 32);
        f32x4 v0 = pA[0], v1 = pA[1];
        s16x8 ahi, alo;
        cvt_hilo(v0, v1, &ahi, &alo);
        int ksg = kh * 12 + kl;
        s16x8 bh[8];
#pragma unroll
        for (int nt = 0; nt < 8; nt++)
            bh[nt] = *(const s16x8*)(wthi + ((size_t)(nt * 24 + ksg) * 64 + lane) * 8);
#pragma unroll
        for (int nt = 0; nt < 8; nt++) {
            acc[nt] = __builtin_amdgcn_mfma_f32_16x16x32_bf16(ahi, bh[nt], acc[nt], 0, 0, 0);
            acc[nt] = __builtin_amdgcn_mfma_f32_16x16x32_bf16(alo, bh[nt], acc[nt], 0, 0, 0);
        }
    }
    // D layout: col = lane&15, row = quad*4 + r.  bias folded into kh==0 half.
#pragma unroll
    for (int nt = 0; nt < 8; nt++) {
        int col = nt * 16 + m;
        float bv = kh ? 0.f : bias[col];
#pragma unroll
        for (int r = 0; r < 4; r++) {
            size_t grow = growbase + quad * 4 + r;
            dst[grow * D_ + col] = acc[nt][r] + bv;
        }
    }
}

// ---------------- norm over sequence axis: inv[bk*128+d] ----------------
__global__ __launch_bounds__(1024) void norm_inv_k(
    const float* __restrict__ x0, const float* __restrict__ x1, float* __restrict__ inv) {
    __shared__ float red[1024];
    int bk = blockIdx.x, t = threadIdx.x;
    int d = t & 127, seg = t >> 7;
    int L; size_t rowbase;
    if (bk < 96)       { L = NQ; rowbase = (size_t)bk * NQ; }
    else if (bk < 192) { L = LP; rowbase = QROWS + (size_t)(bk - 96) * LP; }
    else               { L = LP; rowbase = QROWS + PROWS + (size_t)(bk - 192) * LP; }
    float s = 0.f;
    for (int l = seg; l < L; l += 8) {
        size_t o = (rowbase + l) * D_ + d;
        float v = x0[o] + x1[o];
        s += v * v;
    }
    red[t] = s;
    __syncthreads();
    if (t < 128) {
        float tot = 0.f;
#pragma unroll
        for (int sg = 0; sg < 8; sg++) tot += red[t + sg * 128];
        inv[(size_t)bk * D_ + t] = 1.0f / fmaxf(sqrtf(tot), 1e-12f);
    }
}

// ---------------- scale + bf16 + scatter into fragment layouts ----------------
// qfrag: [qp(48)][mt(5)][ks(4)][lane(64)][8]   (prow = (b&1)*35 + l; pads left garbage)
// pfrag: [side*96+pb][nt(12)][ks(4)][lane(64)][8] (pads left garbage — masked in interact)
__global__ __launch_bounds__(256) void scatter_k(
    const float* __restrict__ x0, const float* __restrict__ x1, const float* __restrict__ inv,
    unsigned short* __restrict__ qfrag, unsigned short* __restrict__ pfrag) {
    int idx = blockIdx.x * 256 + threadIdx.x;            // NROWS*128 exactly
    int row = idx >> 7, d = idx & 127;
    int ks = d >> 5, quad = (d >> 3) & 3, j = d & 7;
    int bk; unsigned short* dest;
    if (row < QROWS) {
        int b = row / 35, l = row - b * 35;
        bk = b;
        int qp = b >> 1, prow = (b & 1) * 35 + l;
        int mt = prow >> 4, mm = prow & 15;
        dest = qfrag + (((size_t)((qp * 5 + mt) * 4 + ks) * 64 + quad * 16 + mm) * 8 + j);
    } else if (row < QROWS + PROWS) {
        int r2 = row - QROWS;
        int b = r2 / 180, l = r2 - b * 180;
        bk = 96 + b;
        int nt = l >> 4, mm = l & 15;
        dest = pfrag + (((size_t)((b * 12 + nt) * 4 + ks) * 64 + quad * 16 + mm) * 8 + j);
    } else {
        int r2 = row - (QROWS + PROWS);
        int b = r2 / 180, l = r2 - b * 180;
        bk = 192 + b;
        int nt = l >> 4, mm = l & 15;
        dest = pfrag + (((size_t)(((96 + b) * 12 + nt) * 4 + ks) * 64 + quad * 16 + mm) * 8 + j);
    }
    float v = (x0[idx] + x1[idx]) * inv[(size_t)bk * D_ + d];
    *dest = f2bf(v);
}

// ---------------- late interaction: block = 4 waves sharing one p-block (LDS) ----------------
__global__ __launch_bounds__(256) void interact_k(
    const unsigned short* __restrict__ qfrag, const unsigned short* __restrict__ pfrag,
    const unsigned char* __restrict__ maskc, float* __restrict__ out) {
    __shared__ unsigned short plds[24576];               // 12nt * 4ks * 64 * 8 = 48 KB
    int wave = threadIdx.x >> 6, lane = threadIdx.x & 63;
    int b = blockIdx.x;                                  // 2304 blocks
    int pb = b / 24;
    int r = b - pb * 24;
    int side = r / 12, qg = r - side * 12;
    int qp = qg * 4 + wave;
    int m = lane & 15, quad = lane >> 4;

    // cooperative stage of the shared p fragment block
    {
        const f32x4* srcv = (const f32x4*)(pfrag + (size_t)(side * 96 + pb) * 24576);
        f32x4* dstv = (f32x4*)plds;
#pragma unroll
        for (int i = 0; i < 12; i++)
            dstv[threadIdx.x + i * 256] = srcv[threadIdx.x + i * 256];
    }

    // q fragments into registers (overlaps with staging)
    s16x8 a[5][4];
    const unsigned short* qbase = qfrag + (size_t)qp * 10240;   // 5*4*64*8
#pragma unroll
    for (int mt = 0; mt < 5; mt++)
#pragma unroll
        for (int ks = 0; ks < 4; ks++)
            a[mt][ks] = *(const s16x8*)(qbase + ((size_t)(mt * 4 + ks) * 64 + lane) * 8);

    const unsigned char* mk = maskc + (size_t)(side * 96 + pb) * LP;
    __syncthreads();

    float rmax[5][4];
#pragma unroll
    for (int mt = 0; mt < 5; mt++)
#pragma unroll
        for (int rr = 0; rr < 4; rr++) rmax[mt][rr] = NEGF;

    for (int nt = 0; nt < 12; nt++) {
        int l = nt * 16 + m;
        int lc = l < LP ? l : LP - 1;
        bool valid = (l < LP) && (mk[lc] != 0);
        s16x8 bfr[4];
#pragma unroll
        for (int ks = 0; ks < 4; ks++)
            bfr[ks] = *(const s16x8*)(plds + ((size_t)(nt * 4 + ks) * 64 + lane) * 8);
#pragma unroll
        for (int mt = 0; mt < 5; mt++) {
            f32x4 acc = (f32x4){0.f, 0.f, 0.f, 0.f};
#pragma unroll
            for (int ks = 0; ks < 4; ks++)
                acc = __builtin_amdgcn_mfma_f32_16x16x32_bf16(a[mt][ks], bfr[ks], acc, 0, 0, 0);
#pragma unroll
            for (int rr = 0; rr < 4; rr++) {
                float v = valid ? acc[rr] : NEGF;
                rmax[mt][rr] = fmaxf(rmax[mt][rr], v);
            }
        }
    }

#pragma unroll
    for (int mt = 0; mt < 5; mt++)
#pragma unroll
        for (int rr = 0; rr < 4; rr++) {
            float v = rmax[mt][rr];
            v = fmaxf(v, __shfl_xor(v, 1));
            v = fmaxf(v, __shfl_xor(v, 2));
            v = fmaxf(v, __shfl_xor(v, 4));
            v = fmaxf(v, __shfl_xor(v, 8));
            rmax[mt][rr] = v;
        }
    float s0 = 0.f, s1 = 0.f;
#pragma unroll
    for (int mt = 0; mt < 5; mt++)
#pragma unroll
        for (int rr = 0; rr < 4; rr++) {
            int prow = mt * 16 + quad * 4 + rr;
            float v = rmax[mt][rr];
            if (prow < 35) s0 += v;
            else if (prow < 70) s1 += v;
        }
    s0 += __shfl_xor(s0, 16); s0 += __shfl_xor(s0, 32);
    s1 += __shfl_xor(s1, 16); s1 += __shfl_xor(s1, 32);
    if (lane == 0) {
        int qb0 = qp * 2, qb1 = qp * 2 + 1;
        out[(size_t)qb0 * (2 * B_) + side * B_ + pb] = s0;
        out[(size_t)qb1 * (2 * B_) + side * B_ + pb] = s1;
    }
}

// ---------------- launch ----------------
extern "C" void kernel_launch(void* const* d_in, const int* in_sizes, int n_in,
                              void* d_out, int out_size, void* d_ws, size_t ws_size,
                              hipStream_t stream) {
    const float* qh   = (const float*)d_in[0];
    const float* ph   = (const float*)d_in[1];
    const float* nh   = (const float*)d_in[2];
    const float* W    = (const float*)d_in[3];
    const float* bias = (const float*)d_in[4];
    const void* pmask = d_in[5];
    const void* nmask = d_in[6];
    float* out = (float*)d_out;
    char* ws = (char*)d_ws;

    constexpr size_t CTRL_OFF  = 0;
    constexpr size_t WTHI_OFF  = 256;                                   // 196608 B
    constexpr size_t MASKC_OFF = WTHI_OFF + 196608;                     // 34560 B
    constexpr size_t INV_OFF   = MASKC_OFF + 34560 + 128;
    constexpr size_t QFRAG_OFF = INV_OFF + 288 * 128 * 4;               // 983040 B
    constexpr size_t PFRAG_OFF = QFRAG_OFF + 983040;                    // 9437184 B
    constexpr size_t X0_OFF    = PFRAG_OFF + 9437184;
    constexpr size_t X1_OFF    = X0_OFF + (size_t)NROWS * D_ * 4;

    unsigned int* ctrl     = (unsigned int*)(ws + CTRL_OFF);
    unsigned short* wthi   = (unsigned short*)(ws + WTHI_OFF);
    unsigned char* maskc   = (unsigned char*)(ws + MASKC_OFF);
    float* inv             = (float*)(ws + INV_OFF);
    unsigned short* qfrag  = (unsigned short*)(ws + QFRAG_OFF);
    unsigned short* pfrag  = (unsigned short*)(ws + PFRAG_OFF);
    float* x0              = (float*)(ws + X0_OFF);
    float* x1              = (float*)(ws + X1_OFF);

    hipMemsetAsync(ws + CTRL_OFF, 0, 64, stream);

    mask_detect<<<(B_ * LP + 255) / 256, 256, 0, stream>>>((const unsigned char*)pmask, ctrl);
    mask_canon<<<(2 * B_ * LP + 255) / 256, 256, 0, stream>>>(pmask, nmask, ctrl, maskc);
    wt_build<<<48, 256, 0, stream>>>(W, wthi);
    proj_k<<<1185, 256, 0, stream>>>(qh, ph, nh, wthi, bias, x0, x1);
    norm_inv_k<<<288, 1024, 0, stream>>>(x0, x1, inv);
    scatter_k<<<(NROWS * D_) / 256, 256, 0, stream>>>(x0, x1, inv, qfrag, pfrag);
    interact_k<<<2304, 256, 0, stream>>>(qfrag, pfrag, maskc, out);
}

// Round 4
// 237.687 us; speedup vs baseline: 1.2658x; 1.2658x over previous
//
#include <hip/hip_runtime.h>

typedef __attribute__((ext_vector_type(4))) float f32x4;
typedef __attribute__((ext_vector_type(8))) short s16x8;
typedef __attribute__((ext_vector_type(4))) short s16x4;
typedef __bf16 bf16x4 __attribute__((ext_vector_type(4)));

#define B_   96
#define NQ   35
#define LP   180
#define H_   768
#define D_   128
#define NEGF (-1e30f)

#define NROWS 37920
#define QROWS 3360
#define PROWS 17280

__device__ __forceinline__ unsigned short f2bf(float f) {
    return __builtin_bit_cast(unsigned short, (__bf16)f);
}

// split two f32x4 into bf16 hi + lo fragments (native packed cvt on gfx950)
__device__ __forceinline__ void cvt_hilo(f32x4 v0, f32x4 v1, s16x8* hi, s16x8* lo) {
    bf16x4 h0 = __builtin_convertvector(v0, bf16x4);
    bf16x4 h1 = __builtin_convertvector(v1, bf16x4);
    f32x4 r0 = v0 - __builtin_convertvector(h0, f32x4);
    f32x4 r1 = v1 - __builtin_convertvector(h1, f32x4);
    bf16x4 l0 = __builtin_convertvector(r0, bf16x4);
    bf16x4 l1 = __builtin_convertvector(r1, bf16x4);
    s16x4 h0s = __builtin_bit_cast(s16x4, h0), h1s = __builtin_bit_cast(s16x4, h1);
    s16x4 l0s = __builtin_bit_cast(s16x4, l0), l1s = __builtin_bit_cast(s16x4, l1);
    *hi = __builtin_shufflevector(h0s, h1s, 0, 1, 2, 3, 4, 5, 6, 7);
    *lo = __builtin_shufflevector(l0s, l1s, 0, 1, 2, 3, 4, 5, 6, 7);
}

// ---------------- mask dtype detection + canonicalization ----------------
__global__ void mask_detect(const unsigned char* __restrict__ mp, unsigned int* __restrict__ ctrl) {
    int i = blockIdx.x * 256 + threadIdx.x;
    if (i >= B_ * LP) return;
    unsigned char v = mp[i];
    if (v) {
        if ((i & 3) == 1) atomicAdd(&ctrl[0], 1u);  // 1-byte layout (bool/int8)
        if ((i & 3) == 3) atomicAdd(&ctrl[1], 1u);  // float32
        if ((i & 7) == 4) atomicAdd(&ctrl[2], 1u);  // int32
    }
}

__global__ void mask_canon(const void* __restrict__ pm, const void* __restrict__ nm,
                           const unsigned int* __restrict__ ctrl, unsigned char* __restrict__ outm) {
    int i = blockIdx.x * 256 + threadIdx.x;
    if (i >= 2 * B_ * LP) return;
    const void* src = (i < B_ * LP) ? pm : nm;
    int j = (i < B_ * LP) ? i : i - B_ * LP;
    unsigned int c1 = ctrl[0], c3 = ctrl[1], c4 = ctrl[2];
    bool bit;
    if (c1 > 0)       bit = ((const unsigned char*)src)[j] != 0;
    else if (c3 > 0)  bit = ((const float*)src)[j] != 0.0f;
    else if (c4 > 0)  bit = ((const int*)src)[j] != 0;
    else              bit = ((const long long*)src)[j] != 0;
    outm[i] = bit ? 1 : 0;
}

// ---------------- W -> fragment-ordered bf16 (hi only) ----------------
__global__ void wt_build(const float* __restrict__ W, unsigned short* __restrict__ wthi) {
    int tid = blockIdx.x * 256 + threadIdx.x;            // 12288 total
    int nt = tid / (24 * 64);
    int r = tid - nt * 24 * 64;
    int ks = r / 64, lane = r - ks * 64;
    int m = lane & 15, quad = lane >> 4;
    unsigned short* o = wthi + (size_t)tid * 8;
#pragma unroll
    for (int j = 0; j < 8; j++) {
        int k = ks * 32 + quad * 8 + j;
        o[j] = f2bf(W[(size_t)k * D_ + nt * 16 + m]);
    }
}

// ---------------- projection GEMM: 16-row tiles, K-split x2 ----------------
__global__ __launch_bounds__(256) void proj_k(
    const float* __restrict__ qh, const float* __restrict__ ph, const float* __restrict__ nh,
    const unsigned short* __restrict__ wthi, const float* __restrict__ bias,
    float* __restrict__ x0, float* __restrict__ x1) {
    int wave = threadIdx.x >> 6, lane = threadIdx.x & 63;
    int w = blockIdx.x * 4 + wave;                       // 4740 exactly
    int rg = w >> 1, kh = w & 1;
    const float* src; int row0l; size_t growbase;
    if (rg < 210)       { src = qh; row0l = rg * 16;          growbase = row0l; }
    else if (rg < 1290) { src = ph; row0l = (rg - 210) * 16;  growbase = QROWS + row0l; }
    else                { src = nh; row0l = (rg - 1290) * 16; growbase = QROWS + PROWS + row0l; }
    float* dst = kh ? x1 : x0;
    int m = lane & 15, quad = lane >> 4;
    const float* ap = src + (size_t)(row0l + m) * H_ + kh * 384 + quad * 8;

    f32x4 acc[8];
#pragma unroll
    for (int nt = 0; nt < 8; nt++) acc[nt] = (f32x4){0.f, 0.f, 0.f, 0.f};

#pragma unroll 2
    for (int kl = 0; kl < 12; kl++) {
        const f32x4* pA = (const f32x4*)(ap + kl * 32);
        f32x4 v0 = pA[0], v1 = pA[1];
        s16x8 ahi, alo;
        cvt_hilo(v0, v1, &ahi, &alo);
        int ksg = kh * 12 + kl;
        s16x8 bh[8];
#pragma unroll
        for (int nt = 0; nt < 8; nt++)
            bh[nt] = *(const s16x8*)(wthi + ((size_t)(nt * 24 + ksg) * 64 + lane) * 8);
#pragma unroll
        for (int nt = 0; nt < 8; nt++) {
            acc[nt] = __builtin_amdgcn_mfma_f32_16x16x32_bf16(ahi, bh[nt], acc[nt], 0, 0, 0);
            acc[nt] = __builtin_amdgcn_mfma_f32_16x16x32_bf16(alo, bh[nt], acc[nt], 0, 0, 0);
        }
    }
#pragma unroll
    for (int nt = 0; nt < 8; nt++) {
        int col = nt * 16 + m;
        float bv = kh ? 0.f : bias[col];
#pragma unroll
        for (int r = 0; r < 4; r++) {
            size_t grow = growbase + quad * 4 + r;
            dst[grow * D_ + col] = acc[nt][r] + bv;
        }
    }
}

// ---------------- norm over sequence axis: inv[bk*128+d] ----------------
__global__ __launch_bounds__(1024) void norm_inv_k(
    const float* __restrict__ x0, const float* __restrict__ x1, float* __restrict__ inv) {
    __shared__ float red[1024];
    int bk = blockIdx.x, t = threadIdx.x;
    int d = t & 127, seg = t >> 7;
    int L; size_t rowbase;
    if (bk < 96)       { L = NQ; rowbase = (size_t)bk * NQ; }
    else if (bk < 192) { L = LP; rowbase = QROWS + (size_t)(bk - 96) * LP; }
    else               { L = LP; rowbase = QROWS + PROWS + (size_t)(bk - 192) * LP; }
    float s = 0.f;
    for (int l = seg; l < L; l += 8) {
        size_t o = (rowbase + l) * D_ + d;
        float v = x0[o] + x1[o];
        s += v * v;
    }
    red[t] = s;
    __syncthreads();
    if (t < 128) {
        float tot = 0.f;
#pragma unroll
        for (int sg = 0; sg < 8; sg++) tot += red[t + sg * 128];
        inv[(size_t)bk * D_ + t] = 1.0f / fmaxf(sqrtf(tot), 1e-12f);
    }
}

// ---------------- scale + bf16 + scatter into fragment layouts ----------------
// qfrag: [qp(48)][mt(5)][ks(4)][lane(64)][8]      (prow = (b&1)*35 + l; pad rows unused)
// pfrag: [pbk(192)][nt(12)][ks(4)][lane(64)][8]   (invalid & pad rows = copy of token 0
//        of the same passage -> interact needs NO mask: duplicate of a valid token never
//        changes the max, and mask[:,0] is guaranteed True by construction)
__global__ __launch_bounds__(256) void scatter_k(
    const float* __restrict__ x0, const float* __restrict__ x1, const float* __restrict__ inv,
    const unsigned char* __restrict__ maskc,
    unsigned short* __restrict__ qfrag, unsigned short* __restrict__ pfrag) {
    int idx = blockIdx.x * 256 + threadIdx.x;            // QROWS*128 + 192*192*128 exactly
    if (idx < QROWS * D_) {
        int row = idx >> 7, d = idx & 127;
        int ks = d >> 5, quad = (d >> 3) & 3, j = d & 7;
        int b = row / 35, l = row - b * 35;
        int qp = b >> 1, prow = (b & 1) * 35 + l;
        int mt = prow >> 4, mm = prow & 15;
        float v = (x0[idx] + x1[idx]) * inv[(size_t)b * D_ + d];
        qfrag[(((size_t)((qp * 5 + mt) * 4 + ks) * 64 + quad * 16 + mm) * 8 + j)] = f2bf(v);
    } else {
        int t = idx - QROWS * D_;
        int d = t & 127;
        int u = t >> 7;                                  // [0, 192*192)
        int l = u % 192, pbk = u / 192;                  // pbk = side*96+pb
        int ks = d >> 5, quad = (d >> 3) & 3, j = d & 7;
        int lsrc = (l < LP && maskc[pbk * LP + l]) ? l : 0;
        size_t o = (QROWS + (size_t)pbk * LP + lsrc) * D_ + d;
        float v = (x0[o] + x1[o]) * inv[(size_t)(96 + pbk) * D_ + d];
        int nt = l >> 4, mm = l & 15;
        pfrag[(((size_t)(pbk * 12 + nt) * 4 + ks) * 64 + quad * 16 + mm) * 8 + j] = f2bf(v);
    }
}

// ---------------- late interaction: mask-free, XCD-pinned, direct L2 loads ----------------
// b: xcd = b&7, i = b>>3; combo c = xcd*24 + i%24 (side,pb); qg = i/24.
// All 12 blocks sharing a combo land on the same XCD -> its 24 combos (1.15 MB of pfrag)
// stay L2-resident; each pfrag block is fetched from HBM once.
__global__ __launch_bounds__(256, 3) void interact_k(
    const unsigned short* __restrict__ qfrag, const unsigned short* __restrict__ pfrag,
    float* __restrict__ out) {
    int wave = threadIdx.x >> 6, lane = threadIdx.x & 63;
    int b = blockIdx.x;                                  // 2304 blocks
    int xcd = b & 7, i = b >> 3;                         // i in [0,288)
    int c = xcd * 24 + (i % 24);                         // [0,192)
    int qg = i / 24;                                     // [0,12)
    int side = c / 96, pb = c - side * 96;
    int qp = qg * 4 + wave;
    int m = lane & 15, quad = lane >> 4;

    const unsigned short* pbase = pfrag + (size_t)c * 24576;
    const unsigned short* qbase = qfrag + (size_t)qp * 10240;

    s16x8 a[5][4];
#pragma unroll
    for (int mt = 0; mt < 5; mt++)
#pragma unroll
        for (int ks = 0; ks < 4; ks++)
            a[mt][ks] = *(const s16x8*)(qbase + ((size_t)(mt * 4 + ks) * 64 + lane) * 8);

    const f32x4 zero4 = (f32x4){0.f, 0.f, 0.f, 0.f};
    float rmax[5][4];
#pragma unroll
    for (int mt = 0; mt < 5; mt++)
#pragma unroll
        for (int rr = 0; rr < 4; rr++) rmax[mt][rr] = NEGF;

    for (int nt = 0; nt < 12; nt++) {
        s16x8 bfr[4];
#pragma unroll
        for (int ks = 0; ks < 4; ks++)
            bfr[ks] = *(const s16x8*)(pbase + ((size_t)(nt * 4 + ks) * 64 + lane) * 8);
#pragma unroll
        for (int mt = 0; mt < 5; mt++) {
            f32x4 acc = __builtin_amdgcn_mfma_f32_16x16x32_bf16(a[mt][0], bfr[0], zero4, 0, 0, 0);
            acc = __builtin_amdgcn_mfma_f32_16x16x32_bf16(a[mt][1], bfr[1], acc, 0, 0, 0);
            acc = __builtin_amdgcn_mfma_f32_16x16x32_bf16(a[mt][2], bfr[2], acc, 0, 0, 0);
            acc = __builtin_amdgcn_mfma_f32_16x16x32_bf16(a[mt][3], bfr[3], acc, 0, 0, 0);
#pragma unroll
            for (int rr = 0; rr < 4; rr++)
                rmax[mt][rr] = fmaxf(rmax[mt][rr], acc[rr]);
        }
    }

#pragma unroll
    for (int mt = 0; mt < 5; mt++)
#pragma unroll
        for (int rr = 0; rr < 4; rr++) {
            float v = rmax[mt][rr];
            v = fmaxf(v, __shfl_xor(v, 1));
            v = fmaxf(v, __shfl_xor(v, 2));
            v = fmaxf(v, __shfl_xor(v, 4));
            v = fmaxf(v, __shfl_xor(v, 8));
            rmax[mt][rr] = v;
        }
    float s0 = 0.f, s1 = 0.f;
#pragma unroll
    for (int mt = 0; mt < 5; mt++)
#pragma unroll
        for (int rr = 0; rr < 4; rr++) {
            int prow = mt * 16 + quad * 4 + rr;
            float v = rmax[mt][rr];
            if (prow < 35) s0 += v;
            else if (prow < 70) s1 += v;
        }
    s0 += __shfl_xor(s0, 16); s0 += __shfl_xor(s0, 32);
    s1 += __shfl_xor(s1, 16); s1 += __shfl_xor(s1, 32);
    if (lane == 0) {
        int qb0 = qp * 2, qb1 = qp * 2 + 1;
        out[(size_t)qb0 * (2 * B_) + side * B_ + pb] = s0;
        out[(size_t)qb1 * (2 * B_) + side * B_ + pb] = s1;
    }
}

// ---------------- launch ----------------
extern "C" void kernel_launch(void* const* d_in, const int* in_sizes, int n_in,
                              void* d_out, int out_size, void* d_ws, size_t ws_size,
                              hipStream_t stream) {
    const float* qh   = (const float*)d_in[0];
    const float* ph   = (const float*)d_in[1];
    const float* nh   = (const float*)d_in[2];
    const float* W    = (const float*)d_in[3];
    const float* bias = (const float*)d_in[4];
    const void* pmask = d_in[5];
    const void* nmask = d_in[6];
    float* out = (float*)d_out;
    char* ws = (char*)d_ws;

    constexpr size_t CTRL_OFF  = 0;
    constexpr size_t WTHI_OFF  = 256;                                   // 196608 B
    constexpr size_t MASKC_OFF = WTHI_OFF + 196608;                     // 34560 B
    constexpr size_t INV_OFF   = MASKC_OFF + 34560 + 128;
    constexpr size_t QFRAG_OFF = INV_OFF + 288 * 128 * 4;               // 983040 B
    constexpr size_t PFRAG_OFF = QFRAG_OFF + 983040;                    // 9437184 B
    constexpr size_t X0_OFF    = PFRAG_OFF + 9437184;
    constexpr size_t X1_OFF    = X0_OFF + (size_t)NROWS * D_ * 4;

    unsigned int* ctrl     = (unsigned int*)(ws + CTRL_OFF);
    unsigned short* wthi   = (unsigned short*)(ws + WTHI_OFF);
    unsigned char* maskc   = (unsigned char*)(ws + MASKC_OFF);
    float* inv             = (float*)(ws + INV_OFF);
    unsigned short* qfrag  = (unsigned short*)(ws + QFRAG_OFF);
    unsigned short* pfrag  = (unsigned short*)(ws + PFRAG_OFF);
    float* x0              = (float*)(ws + X0_OFF);
    float* x1              = (float*)(ws + X1_OFF);

    hipMemsetAsync(ws + CTRL_OFF, 0, 64, stream);

    mask_detect<<<(B_ * LP + 255) / 256, 256, 0, stream>>>((const unsigned char*)pmask, ctrl);
    mask_canon<<<(2 * B_ * LP + 255) / 256, 256, 0, stream>>>(pmask, nmask, ctrl, maskc);
    wt_build<<<48, 256, 0, stream>>>(W, wthi);
    proj_k<<<1185, 256, 0, stream>>>(qh, ph, nh, wthi, bias, x0, x1);
    norm_inv_k<<<288, 1024, 0, stream>>>(x0, x1, inv);
    // QROWS*128 + 192*192*128 = 430080 + 4718592 = 5148672 = 20112 * 256
    scatter_k<<<20112, 256, 0, stream>>>(x0, x1, inv, maskc, qfrag, pfrag);
    interact_k<<<2304, 256, 0, stream>>>(qfrag, pfrag, out);
}

// Round 5
// 218.701 us; speedup vs baseline: 1.3757x; 1.0868x over previous
//
#include <hip/hip_runtime.h>

typedef __attribute__((ext_vector_type(4))) float f32x4;
typedef __attribute__((ext_vector_type(8))) short s16x8;
typedef __attribute__((ext_vector_type(4))) short s16x4;
typedef __bf16 bf16x4 __attribute__((ext_vector_type(4)));

#define B_   96
#define NQ   35
#define LP   180
#define H_   768
#define D_   128
#define NEGF (-1e30f)

#define NROWS 37920
#define QROWS 3360
#define PROWS 17280

__device__ __forceinline__ unsigned short f2bf(float f) {
    return __builtin_bit_cast(unsigned short, (__bf16)f);
}

__device__ __forceinline__ void cvt_hilo(f32x4 v0, f32x4 v1, s16x8* hi, s16x8* lo) {
    bf16x4 h0 = __builtin_convertvector(v0, bf16x4);
    bf16x4 h1 = __builtin_convertvector(v1, bf16x4);
    f32x4 r0 = v0 - __builtin_convertvector(h0, f32x4);
    f32x4 r1 = v1 - __builtin_convertvector(h1, f32x4);
    bf16x4 l0 = __builtin_convertvector(r0, bf16x4);
    bf16x4 l1 = __builtin_convertvector(r1, bf16x4);
    s16x4 h0s = __builtin_bit_cast(s16x4, h0), h1s = __builtin_bit_cast(s16x4, h1);
    s16x4 l0s = __builtin_bit_cast(s16x4, l0), l1s = __builtin_bit_cast(s16x4, l1);
    *hi = __builtin_shufflevector(h0s, h1s, 0, 1, 2, 3, 4, 5, 6, 7);
    *lo = __builtin_shufflevector(l0s, l1s, 0, 1, 2, 3, 4, 5, 6, 7);
}

// ---------------- prep: wt_build (blocks 0-47) + ssq zero (48-191) + mask detect (192) ----
__global__ __launch_bounds__(256) void prep_k(
    const float* __restrict__ W, unsigned short* __restrict__ wthi,
    const unsigned int* __restrict__ pmask_w, unsigned int* __restrict__ ctrl,
    float* __restrict__ ssq) {
    __shared__ unsigned int rr[256];
    int b = blockIdx.x, t = threadIdx.x;
    if (b < 48) {
        int tid = b * 256 + t;
        int nt = tid / (24 * 64);
        int r = tid - nt * 24 * 64;
        int ks = r / 64, lane = r - ks * 64;
        int m = lane & 15, quad = lane >> 4;
        unsigned short* o = wthi + (size_t)tid * 8;
#pragma unroll
        for (int j = 0; j < 8; j++) {
            int k = ks * 32 + quad * 8 + j;
            o[j] = f2bf(W[(size_t)k * D_ + nt * 16 + m]);
        }
    } else if (b < 192) {
        ssq[(b - 48) * 256 + t] = 0.f;       // 144*256 = 36864 exactly
    } else {
        // byte-pattern detection over first 17280 bytes (4320 dwords) of pos mask
        unsigned int f1 = 0, f3 = 0, f4 = 0;
        for (int w = t; w < 4320; w += 256) {
            unsigned int v = pmask_w[w];
            f1 |= v & 0x0000ff00u;                 // byte index %4==1  -> 1-byte layout
            f3 |= v & 0xff000000u;                 // byte index %4==3  -> float32
            if (w & 1) f4 |= v & 0x000000ffu;      // byte index %8==4  -> int32
        }
        rr[t] = f1; __syncthreads();
        for (int s2 = 128; s2; s2 >>= 1) { if (t < s2) rr[t] |= rr[t + s2]; __syncthreads(); }
        if (!t) ctrl[0] = rr[0];
        __syncthreads();
        rr[t] = f3; __syncthreads();
        for (int s2 = 128; s2; s2 >>= 1) { if (t < s2) rr[t] |= rr[t + s2]; __syncthreads(); }
        if (!t) ctrl[1] = rr[0];
        __syncthreads();
        rr[t] = f4; __syncthreads();
        for (int s2 = 128; s2; s2 >>= 1) { if (t < s2) rr[t] |= rr[t + s2]; __syncthreads(); }
        if (!t) ctrl[2] = rr[0];
    }
}

// ---------------- proj: block = 16-row group, 4 waves = K-quarters, LDS combine ----------
// Epilogue: x = sum of 4 partials + bias (fp32 out) and atomicAdd of per-(bk,d)
// sum-of-squares into ssq (sequence-axis norm fused). Blocks >= 2370 do mask canon.
__global__ __launch_bounds__(256) void proj_k(
    const float* __restrict__ qh, const float* __restrict__ ph, const float* __restrict__ nh,
    const unsigned short* __restrict__ wthi, const float* __restrict__ bias,
    float* __restrict__ x, float* __restrict__ ssq,
    const void* __restrict__ pm, const void* __restrict__ nm,
    const unsigned int* __restrict__ ctrl, unsigned char* __restrict__ maskc) {
    __shared__ f32x4 part[4][8][64];                 // 32 KB
    int b = blockIdx.x;
    if (b >= 2370) {                                 // ---- mask canon: 135 blocks exact ----
        int i = (b - 2370) * 256 + threadIdx.x;      // < 34560
        const void* src = (i < B_ * LP) ? pm : nm;
        int j = (i < B_ * LP) ? i : i - B_ * LP;
        unsigned int c1 = ctrl[0], c3 = ctrl[1], c4 = ctrl[2];
        bool bit;
        if (c1 > 0)       bit = ((const unsigned char*)src)[j] != 0;
        else if (c3 > 0)  bit = ((const float*)src)[j] != 0.0f;
        else if (c4 > 0)  bit = ((const int*)src)[j] != 0;
        else              bit = ((const long long*)src)[j] != 0;
        maskc[i] = bit ? 1 : 0;
        return;
    }
    int wave = threadIdx.x >> 6, lane = threadIdx.x & 63;
    int rg = b;
    const float* src; int row0l; int growbase;
    if (rg < 210)       { src = qh; row0l = rg * 16;          growbase = row0l; }
    else if (rg < 1290) { src = ph; row0l = (rg - 210) * 16;  growbase = QROWS + row0l; }
    else                { src = nh; row0l = (rg - 1290) * 16; growbase = QROWS + PROWS + row0l; }
    int m = lane & 15, quad = lane >> 4;
    const float* ap = src + (size_t)(row0l + m) * H_ + wave * 192 + quad * 8;

    f32x4 acc[8];
#pragma unroll
    for (int nt = 0; nt < 8; nt++) acc[nt] = (f32x4){0.f, 0.f, 0.f, 0.f};

#pragma unroll 2
    for (int kl = 0; kl < 6; kl++) {
        const f32x4* pA = (const f32x4*)(ap + kl * 32);
        f32x4 v0 = pA[0], v1 = pA[1];
        s16x8 ahi, alo;
        cvt_hilo(v0, v1, &ahi, &alo);
        int ksg = wave * 6 + kl;
        s16x8 bh[8];
#pragma unroll
        for (int nt = 0; nt < 8; nt++)
            bh[nt] = *(const s16x8*)(wthi + ((size_t)(nt * 24 + ksg) * 64 + lane) * 8);
#pragma unroll
        for (int nt = 0; nt < 8; nt++) {
            acc[nt] = __builtin_amdgcn_mfma_f32_16x16x32_bf16(ahi, bh[nt], acc[nt], 0, 0, 0);
            acc[nt] = __builtin_amdgcn_mfma_f32_16x16x32_bf16(alo, bh[nt], acc[nt], 0, 0, 0);
        }
    }
#pragma unroll
    for (int nt = 0; nt < 8; nt++) part[wave][nt][lane] = acc[nt];
    __syncthreads();

    // batch mapping for this 16-row group (at most 2 batches)
    int bk0, bk1, b1start;
    if (growbase < QROWS)              { bk0 = growbase / 35;  bk1 = (growbase + 15) / 35;
                                         b1start = bk1 * 35; }
    else if (growbase < QROWS + PROWS) { int r0 = growbase - QROWS;
                                         bk0 = 96 + r0 / 180;  bk1 = 96 + (r0 + 15) / 180;
                                         b1start = QROWS + (bk1 - 96) * 180; }
    else                               { int r0 = growbase - QROWS - PROWS;
                                         bk0 = 192 + r0 / 180; bk1 = 192 + (r0 + 15) / 180;
                                         b1start = QROWS + PROWS + (bk1 - 192) * 180; }

#pragma unroll
    for (int q2 = 0; q2 < 2; q2++) {
        int nt = wave * 2 + q2;
        f32x4 s = part[0][nt][lane];
        s += part[1][nt][lane];
        s += part[2][nt][lane];
        s += part[3][nt][lane];
        int col = nt * 16 + m;
        float bv = bias[col];
        float slo = 0.f, shi = 0.f;
#pragma unroll
        for (int r = 0; r < 4; r++) {
            int grow = growbase + quad * 4 + r;
            float v = s[r] + bv;
            x[(size_t)grow * D_ + col] = v;
            float v2 = v * v;
            if (bk1 > bk0 && grow >= b1start) shi += v2; else slo += v2;
        }
        slo += __shfl_xor(slo, 16); slo += __shfl_xor(slo, 32);
        if (quad == 0) atomicAdd(ssq + (size_t)bk0 * D_ + col, slo);
        if (bk1 > bk0) {
            shi += __shfl_xor(shi, 16); shi += __shfl_xor(shi, 32);
            if (quad == 0) atomicAdd(ssq + (size_t)bk1 * D_ + col, shi);
        }
    }
}

// ---------------- scale (inline rsqrt) + bf16 + scatter into fragment layouts ----------
// qfrag: [qp(48)][mt(5)][ks(4)][lane(64)][8]      (prow = (b&1)*35 + l)
// pfrag: [pbk(192)][nt(12)][ks(4)][lane(64)][8]   (invalid & pad rows = token 0 copy ->
//        interact needs no mask; mask[:,0] is guaranteed True)
__global__ __launch_bounds__(256) void scatter_k(
    const float* __restrict__ x, const float* __restrict__ ssq,
    const unsigned char* __restrict__ maskc,
    unsigned short* __restrict__ qfrag, unsigned short* __restrict__ pfrag) {
    int idx = blockIdx.x * 256 + threadIdx.x;        // QROWS*128 + 192*192*128 exactly
    if (idx < QROWS * D_) {
        int row = idx >> 7, d = idx & 127;
        int ks = d >> 5, quad = (d >> 3) & 3, j = d & 7;
        int b = row / 35, l = row - b * 35;
        int qp = b >> 1, prow = (b & 1) * 35 + l;
        int mt = prow >> 4, mm = prow & 15;
        float iv = rsqrtf(fmaxf(ssq[(size_t)b * D_ + d], 1e-24f));
        float v = x[idx] * iv;
        qfrag[(((size_t)((qp * 5 + mt) * 4 + ks) * 64 + quad * 16 + mm) * 8 + j)] = f2bf(v);
    } else {
        int t = idx - QROWS * D_;
        int d = t & 127;
        int u = t >> 7;                              // [0, 192*192)
        int l = u % 192, pbk = u / 192;              // pbk = side*96+pb
        int ks = d >> 5, quad = (d >> 3) & 3, j = d & 7;
        int lsrc = (l < LP && maskc[pbk * LP + l]) ? l : 0;
        size_t o = (QROWS + (size_t)pbk * LP + lsrc) * D_ + d;
        float iv = rsqrtf(fmaxf(ssq[(size_t)(96 + pbk) * D_ + d], 1e-24f));
        float v = x[o] * iv;
        int nt = l >> 4, mm = l & 15;
        pfrag[(((size_t)(pbk * 12 + nt) * 4 + ks) * 64 + quad * 16 + mm) * 8 + j] = f2bf(v);
    }
}

// ---------------- late interaction: mask-free, XCD-pinned, direct L2 loads -------------
__global__ __launch_bounds__(256, 3) void interact_k(
    const unsigned short* __restrict__ qfrag, const unsigned short* __restrict__ pfrag,
    float* __restrict__ out) {
    int wave = threadIdx.x >> 6, lane = threadIdx.x & 63;
    int b = blockIdx.x;                              // 2304 blocks
    int xcd = b & 7, i = b >> 3;                     // i in [0,288)
    int c = xcd * 24 + (i % 24);                     // [0,192)
    int qg = i / 24;                                 // [0,12)
    int side = c / 96, pb = c - side * 96;
    int qp = qg * 4 + wave;
    int m = lane & 15, quad = lane >> 4;

    const unsigned short* pbase = pfrag + (size_t)c * 24576;
    const unsigned short* qbase = qfrag + (size_t)qp * 10240;

    s16x8 a[5][4];
#pragma unroll
    for (int mt = 0; mt < 5; mt++)
#pragma unroll
        for (int ks = 0; ks < 4; ks++)
            a[mt][ks] = *(const s16x8*)(qbase + ((size_t)(mt * 4 + ks) * 64 + lane) * 8);

    const f32x4 zero4 = (f32x4){0.f, 0.f, 0.f, 0.f};
    float rmax[5][4];
#pragma unroll
    for (int mt = 0; mt < 5; mt++)
#pragma unroll
        for (int rr = 0; rr < 4; rr++) rmax[mt][rr] = NEGF;

    for (int nt = 0; nt < 12; nt++) {
        s16x8 bfr[4];
#pragma unroll
        for (int ks = 0; ks < 4; ks++)
            bfr[ks] = *(const s16x8*)(pbase + ((size_t)(nt * 4 + ks) * 64 + lane) * 8);
#pragma unroll
        for (int mt = 0; mt < 5; mt++) {
            f32x4 acc = __builtin_amdgcn_mfma_f32_16x16x32_bf16(a[mt][0], bfr[0], zero4, 0, 0, 0);
            acc = __builtin_amdgcn_mfma_f32_16x16x32_bf16(a[mt][1], bfr[1], acc, 0, 0, 0);
            acc = __builtin_amdgcn_mfma_f32_16x16x32_bf16(a[mt][2], bfr[2], acc, 0, 0, 0);
            acc = __builtin_amdgcn_mfma_f32_16x16x32_bf16(a[mt][3], bfr[3], acc, 0, 0, 0);
#pragma unroll
            for (int rr = 0; rr < 4; rr++)
                rmax[mt][rr] = fmaxf(rmax[mt][rr], acc[rr]);
        }
    }

#pragma unroll
    for (int mt = 0; mt < 5; mt++)
#pragma unroll
        for (int rr = 0; rr < 4; rr++) {
            float v = rmax[mt][rr];
            v = fmaxf(v, __shfl_xor(v, 1));
            v = fmaxf(v, __shfl_xor(v, 2));
            v = fmaxf(v, __shfl_xor(v, 4));
            v = fmaxf(v, __shfl_xor(v, 8));
            rmax[mt][rr] = v;
        }
    float s0 = 0.f, s1 = 0.f;
#pragma unroll
    for (int mt = 0; mt < 5; mt++)
#pragma unroll
        for (int rr = 0; rr < 4; rr++) {
            int prow = mt * 16 + quad * 4 + rr;
            float v = rmax[mt][rr];
            if (prow < 35) s0 += v;
            else if (prow < 70) s1 += v;
        }
    s0 += __shfl_xor(s0, 16); s0 += __shfl_xor(s0, 32);
    s1 += __shfl_xor(s1, 16); s1 += __shfl_xor(s1, 32);
    if (lane == 0) {
        int qb0 = qp * 2, qb1 = qp * 2 + 1;
        out[(size_t)qb0 * (2 * B_) + side * B_ + pb] = s0;
        out[(size_t)qb1 * (2 * B_) + side * B_ + pb] = s1;
    }
}

// ---------------- launch ----------------
extern "C" void kernel_launch(void* const* d_in, const int* in_sizes, int n_in,
                              void* d_out, int out_size, void* d_ws, size_t ws_size,
                              hipStream_t stream) {
    const float* qh   = (const float*)d_in[0];
    const float* ph   = (const float*)d_in[1];
    const float* nh   = (const float*)d_in[2];
    const float* W    = (const float*)d_in[3];
    const float* bias = (const float*)d_in[4];
    const void* pmask = d_in[5];
    const void* nmask = d_in[6];
    float* out = (float*)d_out;
    char* ws = (char*)d_ws;

    constexpr size_t CTRL_OFF  = 0;                          // 256 B
    constexpr size_t WTHI_OFF  = 256;                        // 196608 B
    constexpr size_t MASKC_OFF = WTHI_OFF + 196608;          // 34560 B -> ends 231424
    constexpr size_t SSQ_OFF   = 231424;                     // 147456 B
    constexpr size_t X_OFF     = SSQ_OFF + 147456;           // 19415040 B
    constexpr size_t QFRAG_OFF = X_OFF + (size_t)NROWS * D_ * 4;   // 983040 B
    constexpr size_t PFRAG_OFF = QFRAG_OFF + 983040;         // 9437184 B

    unsigned int* ctrl     = (unsigned int*)(ws + CTRL_OFF);
    unsigned short* wthi   = (unsigned short*)(ws + WTHI_OFF);
    unsigned char* maskc   = (unsigned char*)(ws + MASKC_OFF);
    float* ssq             = (float*)(ws + SSQ_OFF);
    float* x               = (float*)(ws + X_OFF);
    unsigned short* qfrag  = (unsigned short*)(ws + QFRAG_OFF);
    unsigned short* pfrag  = (unsigned short*)(ws + PFRAG_OFF);

    prep_k<<<193, 256, 0, stream>>>(W, wthi, (const unsigned int*)pmask, ctrl, ssq);
    proj_k<<<2370 + 135, 256, 0, stream>>>(qh, ph, nh, wthi, bias, x, ssq,
                                           pmask, nmask, ctrl, maskc);
    // QROWS*128 + 192*192*128 = 5148672 = 20112 * 256
    scatter_k<<<20112, 256, 0, stream>>>(x, ssq, maskc, qfrag, pfrag);
    interact_k<<<2304, 256, 0, stream>>>(qfrag, pfrag, out);
}